// Round 1
// baseline (194.948 us; speedup 1.0000x reference)
//
#include <hip/hip_runtime.h>
#include <hip/hip_bf16.h>

#define EMBED 1536
#define SEQ   896
#define NOUT  5313

// padded head row layout inside wpad / bpad
#define N0 5313
#define N1 1643
#define N2 128
#define W0OFF 0
#define W1OFF 5376
#define W2OFF 7040
#define PTOT  7168

typedef __attribute__((ext_vector_type(8))) short bf16x8;   // 8 bf16 = 4 VGPRs
typedef __attribute__((ext_vector_type(4))) float f32x4;

__device__ __forceinline__ void gload_lds16(const void* g, void* l) {
    __builtin_amdgcn_global_load_lds(
        (const __attribute__((address_space(1))) void*)g,
        (__attribute__((address_space(3))) void*)l, 16, 0, 0);
}

// ---------------- 1) LayerNorm (fp32) -> bf16 xn ----------------
__global__ __launch_bounds__(128) void ln_kernel(
    const float* __restrict__ x, const int* __restrict__ head_idx,
    const float* __restrict__ g0, const float* __restrict__ be0,
    const float* __restrict__ g1, const float* __restrict__ be1,
    const float* __restrict__ g2, const float* __restrict__ be2,
    __hip_bfloat16* __restrict__ xn)
{
    const int row = blockIdx.x;            // 0..3583
    const int b = row / SEQ;
    const int h = head_idx[b];
    const float* gamma = (h == 1) ? g1 : (h == 2) ? g2 : g0;   // h==3: unused downstream
    const float* beta  = (h == 1) ? be1 : (h == 2) ? be2 : be0;
    const float* xr = x + (size_t)row * EMBED;
    const int tid = threadIdx.x;

    float4 v[3];
    float sum = 0.f, sq = 0.f;
#pragma unroll
    for (int i = 0; i < 3; ++i) {
        v[i] = ((const float4*)xr)[tid + i * 128];
        sum += v[i].x + v[i].y + v[i].z + v[i].w;
        sq  += v[i].x * v[i].x + v[i].y * v[i].y + v[i].z * v[i].z + v[i].w * v[i].w;
    }
#pragma unroll
    for (int off = 32; off > 0; off >>= 1) {
        sum += __shfl_down(sum, off);
        sq  += __shfl_down(sq, off);
    }
    __shared__ float s_sum[2], s_sq[2];
    const int wave = tid >> 6, lane = tid & 63;
    if (lane == 0) { s_sum[wave] = sum; s_sq[wave] = sq; }
    __syncthreads();
    const float mu  = (s_sum[0] + s_sum[1]) * (1.f / EMBED);
    const float var = (s_sq[0] + s_sq[1]) * (1.f / EMBED) - mu * mu;
    const float rs  = rsqrtf(var + 1e-5f);

    __hip_bfloat16* xo = xn + (size_t)row * EMBED;
#pragma unroll
    for (int i = 0; i < 3; ++i) {
        const int idx = tid + i * 128;
        float4 gv = ((const float4*)gamma)[idx];
        float4 bv = ((const float4*)beta)[idx];
        union { __hip_bfloat16 h4[4]; short4 s4; } u;
        u.h4[0] = __float2bfloat16((v[i].x - mu) * rs * gv.x + bv.x);
        u.h4[1] = __float2bfloat16((v[i].y - mu) * rs * gv.y + bv.y);
        u.h4[2] = __float2bfloat16((v[i].z - mu) * rs * gv.z + bv.z);
        u.h4[3] = __float2bfloat16((v[i].w - mu) * rs * gv.w + bv.w);
        ((short4*)xo)[idx] = u.s4;
    }
}

// ---------------- 2) W fp32 -> bf16, zero-padded rows ----------------
__global__ __launch_bounds__(256) void wconv_kernel(
    const float* __restrict__ W0, const float* __restrict__ W1,
    const float* __restrict__ W2, __hip_bfloat16* __restrict__ wpad)
{
    const int gid = blockIdx.x * 256 + threadIdx.x;   // PTOT*192 threads
    const int r = gid / 192;
    const int c = (gid - r * 192) * 8;
    const float* src = nullptr;
    if (r < W1OFF)      { if (r < N0) src = W0 + (size_t)r * EMBED; }
    else if (r < W2OFF) { int rr = r - W1OFF; if (rr < N1) src = W1 + (size_t)rr * EMBED; }
    else                { int rr = r - W2OFF; if (rr < N2) src = W2 + (size_t)rr * EMBED; }
    union { __hip_bfloat16 h8[8]; int4 v4; } u;
    if (src) {
        float4 a = ((const float4*)(src + c))[0];
        float4 b = ((const float4*)(src + c))[1];
        u.h8[0] = __float2bfloat16(a.x); u.h8[1] = __float2bfloat16(a.y);
        u.h8[2] = __float2bfloat16(a.z); u.h8[3] = __float2bfloat16(a.w);
        u.h8[4] = __float2bfloat16(b.x); u.h8[5] = __float2bfloat16(b.y);
        u.h8[6] = __float2bfloat16(b.z); u.h8[7] = __float2bfloat16(b.w);
    } else {
        u.v4 = make_int4(0, 0, 0, 0);
    }
    *(int4*)(wpad + (size_t)r * EMBED + c) = u.v4;
}

// ---------------- 3) bias -> padded fp32 ----------------
__global__ __launch_bounds__(256) void biasconv_kernel(
    const float* __restrict__ b0, const float* __restrict__ b1,
    const float* __restrict__ b2, float* __restrict__ bpad)
{
    const int i = blockIdx.x * 256 + threadIdx.x;     // 0..PTOT-1
    float v = 0.f;
    if (i < W1OFF)      { if (i < N0) v = b0[i]; }
    else if (i < W2OFF) { int j = i - W1OFF; if (j < N1) v = b1[j]; }
    else                { int j = i - W2OFF; if (j < N2) v = b2[j]; }
    bpad[i] = v;
}

// ---------------- 4) bf16 MFMA GEMM + bias + softplus + pad ----------------
// grid (42, 7, 4) = (ntile, mtile, batch); block 256 = 4 waves, 128x128 tile
__global__ __launch_bounds__(256, 2) void head_gemm(
    const __hip_bfloat16* __restrict__ xn,   // (4*896, 1536)
    const __hip_bfloat16* __restrict__ wpad, // (7168, 1536) padded bf16
    const float* __restrict__ bpad,          // (7168) padded
    const int* __restrict__ head_idx,
    float* __restrict__ out)                 // (4, 896, 5313)
{
    const int nt = blockIdx.x, mt = blockIdx.y, b = blockIdx.z;
    const int h = head_idx[b];
    int nrows, wbase;
    if (h == 0)      { nrows = N0; wbase = W0OFF; }
    else if (h == 1) { nrows = N1; wbase = W1OFF; }
    else if (h == 2) { nrows = N2; wbase = W2OFF; }
    else             { nrows = 0;  wbase = 0; }

    const int tid = threadIdx.x;
    const int col0 = nt * 128;
    float* outb = out + ((size_t)b * SEQ + (size_t)mt * 128) * NOUT;

    if (col0 >= nrows) {
        // zero-fill tile (also the whole ZeroHead batch)
        for (int i = tid; i < 128 * 128; i += 256) {
            const int r = i >> 7;
            const int cc = col0 + (i & 127);
            if (cc < NOUT) outb[(size_t)r * NOUT + cc] = 0.f;
        }
        return;
    }

    __shared__ __hip_bfloat16 As[128 * 64];   // 16 KB
    __shared__ __hip_bfloat16 Bs[128 * 64];   // 16 KB
    const __hip_bfloat16* Ab = xn + ((size_t)b * SEQ + (size_t)mt * 128) * EMBED;
    const __hip_bfloat16* Bb = wpad + (size_t)(wbase + col0) * EMBED;

    const int wave = tid >> 6, lane = tid & 63;
    const int wm = wave >> 1, wn = wave & 1;         // 2x2 waves of 64x64
    const int fm = lane & 15, quad = lane >> 4;
    const int fsw = fm & 7;                          // XOR swizzle key (row & 7)

    f32x4 acc[4][4] = {};

    for (int kt = 0; kt < EMBED / 64; ++kt) {        // 24 iterations
        const int k0 = kt * 64;
        __syncthreads();                             // prev readers done
#pragma unroll
        for (int i = 0; i < 4; ++i) {                // stage A: 128x64 bf16
            const int c = tid + i * 256;             // LDS chunk 0..1023 (16B each)
            const int arow = c >> 3;
            const int kc = (c & 7) ^ (arow & 7);     // xor-swizzled k-chunk
            gload_lds16(Ab + (size_t)arow * EMBED + k0 + kc * 8, As + c * 8);
        }
#pragma unroll
        for (int i = 0; i < 4; ++i) {                // stage B: 128x64 bf16
            const int c = tid + i * 256;
            const int brow = c >> 3;
            const int kc = (c & 7) ^ (brow & 7);
            gload_lds16(Bb + (size_t)brow * EMBED + k0 + kc * 8, Bs + c * 8);
        }
        __syncthreads();                             // drains vmcnt before barrier
#pragma unroll
        for (int ks = 0; ks < 2; ++ks) {
            bf16x8 af[4], bfr[4];
#pragma unroll
            for (int i = 0; i < 4; ++i)
                af[i] = *(const bf16x8*)&As[(wm * 64 + i * 16 + fm) * 64 +
                                            (((ks << 2) + quad) ^ fsw) * 8];
#pragma unroll
            for (int j = 0; j < 4; ++j)
                bfr[j] = *(const bf16x8*)&Bs[(wn * 64 + j * 16 + fm) * 64 +
                                             (((ks << 2) + quad) ^ fsw) * 8];
#pragma unroll
            for (int i = 0; i < 4; ++i)
#pragma unroll
                for (int j = 0; j < 4; ++j)
                    acc[i][j] = __builtin_amdgcn_mfma_f32_16x16x32_bf16(
                        af[i], bfr[j], acc[i][j], 0, 0, 0);
        }
    }

    // epilogue: bias + softplus, mask padded cols to 0
#pragma unroll
    for (int j = 0; j < 4; ++j) {
        const int lcol = col0 + wn * 64 + j * 16 + fm;
        const bool inb = lcol < NOUT;
        const bool valid = lcol < nrows;
        const float bv = valid ? bpad[wbase + lcol] : 0.f;
#pragma unroll
        for (int i = 0; i < 4; ++i) {
            const int rbase = wm * 64 + i * 16 + quad * 4;
#pragma unroll
            for (int r = 0; r < 4; ++r) {
                if (!inb) continue;
                const float v = acc[i][j][r] + bv;
                // softplus: max(v,0) + log(1 + exp(-|v|)) — overflow-safe
                const float sp = fmaxf(v, 0.f) + __logf(1.f + __expf(-fabsf(v)));
                outb[(size_t)(rbase + r) * NOUT + lcol] = valid ? sp : 0.f;
            }
        }
    }
}

extern "C" void kernel_launch(void* const* d_in, const int* in_sizes, int n_in,
                              void* d_out, int out_size, void* d_ws, size_t ws_size,
                              hipStream_t stream) {
    const float* x   = (const float*)d_in[0];
    const int* hidx  = (const int*)d_in[1];
    const float* g0  = (const float*)d_in[2];
    const float* be0 = (const float*)d_in[3];
    const float* W0  = (const float*)d_in[4];
    const float* b0  = (const float*)d_in[5];
    const float* g1  = (const float*)d_in[6];
    const float* be1 = (const float*)d_in[7];
    const float* W1  = (const float*)d_in[8];
    const float* b1  = (const float*)d_in[9];
    const float* g2  = (const float*)d_in[10];
    const float* be2 = (const float*)d_in[11];
    const float* W2  = (const float*)d_in[12];
    const float* b2  = (const float*)d_in[13];
    float* out = (float*)d_out;

    // workspace layout
    const size_t XN_BYTES   = (size_t)4 * SEQ * EMBED * 2;          // 11,010,048
    const size_t WPAD_BYTES = (size_t)PTOT * EMBED * 2;             // 22,020,096
    __hip_bfloat16* xn   = (__hip_bfloat16*)d_ws;
    __hip_bfloat16* wpad = (__hip_bfloat16*)((char*)d_ws + XN_BYTES);
    float* bpad          = (float*)((char*)d_ws + XN_BYTES + WPAD_BYTES);

    ln_kernel<<<4 * SEQ, 128, 0, stream>>>(x, hidx, g0, be0, g1, be1, g2, be2, xn);
    wconv_kernel<<<(PTOT * 192) / 256, 256, 0, stream>>>(W0, W1, W2, wpad);
    biasconv_kernel<<<PTOT / 256, 256, 0, stream>>>(b0, b1, b2, bpad);
    dim3 grid(42, 7, 4);
    head_gemm<<<grid, 256, 0, stream>>>(xn, wpad, bpad, hidx, out);
}